// Round 1
// 2707.881 us; speedup vs baseline: 1.3139x; 1.3139x over previous
//
#include <hip/hip_runtime.h>

// ---------------- problem constants ----------------
#define T_STEPS 256
#define BATCH   16
#define EMBED   256
#define HIDDEN  512
#define G4      2048      // 4*HIDDEN
#define VOCAB   32000
#define NTOK    4096      // B*T
#define NBLK_SCAN 64

typedef _Float16 f16x8 __attribute__((ext_vector_type(8)));
typedef float    f32x4 __attribute__((ext_vector_type(4)));

// ---------------- ws layout (bytes) ----------------
// Gin   f32 [256][2048][16]   33,554,432
// Wout  f16 [32000][512]      32,768,000
// hs    f16 [4096][512]        4,194,304
// emb   f16 [4096][256]        2,097,152
// Wih   f16 [2][2048][256]     2,097,152
// hpub  f16 [2][16][512]          32,768
// cidt  i32 [256][16]             16,384
// cidr  i32 [4096]                16,384
// flags u32 [257]                  2,048
#define OFF_GIN    0
#define OFF_WOUT   33554432
#define OFF_HS     66322432
#define OFF_EMB    70516736
#define OFF_WIH    72613888
#define OFF_HPUB   74711040
#define OFF_CIDT   74743808
#define OFF_CIDR   74760192
#define OFF_FLAGS  74776576

// ================= prep: dtype conversions, gathers, flag zeroing =================
#define P_SA 4096000
#define P_SB (P_SA + 262144)
#define P_SC (P_SB + 262144)
#define P_SD (P_SC + 4096)
#define P_SE (P_SD + 257)

__global__ __launch_bounds__(256) void prep_kernel(
    const int* __restrict__ x, const int* __restrict__ assign,
    const float* __restrict__ Wih, const float* __restrict__ Wout,
    const float* __restrict__ embt,
    _Float16* __restrict__ wih_h, _Float16* __restrict__ wout_h,
    _Float16* __restrict__ emb_h, int* __restrict__ cids_t,
    int* __restrict__ cid_r, unsigned int* __restrict__ flags)
{
    size_t id = (size_t)blockIdx.x * 256 + threadIdx.x;
    if (id < P_SA) {
        float4 v = ((const float4*)Wout)[id];
        _Float16* o = wout_h + id * 4;
        o[0] = (_Float16)v.x; o[1] = (_Float16)v.y; o[2] = (_Float16)v.z; o[3] = (_Float16)v.w;
    } else if (id < P_SB) {
        size_t j = id - P_SA;
        float4 v = ((const float4*)Wih)[j];
        _Float16* o = wih_h + j * 4;
        o[0] = (_Float16)v.x; o[1] = (_Float16)v.y; o[2] = (_Float16)v.z; o[3] = (_Float16)v.w;
    } else if (id < P_SC) {
        size_t j = id - P_SB;
        int r  = (int)(j >> 6);      // token row 0..4095  (r = b*256+t)
        int e4 = (int)(j & 63);
        float4 v = ((const float4*)(embt + (size_t)x[r] * EMBED))[e4];
        _Float16* o = emb_h + (size_t)r * EMBED + e4 * 4;
        o[0] = (_Float16)v.x; o[1] = (_Float16)v.y; o[2] = (_Float16)v.z; o[3] = (_Float16)v.w;
    } else if (id < P_SD) {
        int j = (int)(id - P_SC);
        int b = j >> 8, t = j & 255;
        int c = assign[x[j]];
        cid_r[j] = c;
        cids_t[t * BATCH + b] = c;
    } else if (id < P_SE) {
        flags[id - P_SD] = 0u;
    }
}

// ================= Gin GEMM: emb[4096,256] x Wih[c][2048,256]^T, cell-selected scatter =================
__global__ __launch_bounds__(256) void gin_gemm_kernel(
    const _Float16* __restrict__ A,      // emb_h [4096][256]
    const _Float16* __restrict__ WihH,   // [2][2048][256]
    const float* __restrict__ bias,      // [2][2048]
    const int* __restrict__ cid_r,       // [4096]
    float* __restrict__ Gin)             // [256][2048][16]
{
    __shared__ __attribute__((aligned(16))) _Float16 As[128][32];
    __shared__ __attribute__((aligned(16))) _Float16 Bs[128][32];
    const int tid = threadIdx.x, lane = tid & 63, w = tid >> 6;
    const int m16 = lane & 15, kq = lane >> 4;
    const int rb = blockIdx.x, nb = blockIdx.y, cell = blockIdx.z;
    const _Float16* Bt = WihH + (size_t)cell * G4 * EMBED;
    f32x4 acc[2][8];
    for (int mt = 0; mt < 2; mt++) for (int nt = 0; nt < 8; nt++) acc[mt][nt] = (f32x4){0.f,0.f,0.f,0.f};

    for (int kt = 0; kt < EMBED; kt += 32) {
        __syncthreads();
        #pragma unroll
        for (int c = tid; c < 512; c += 256) {
            int row = c >> 2, q = c & 3;
            ((uint4*)As)[c] = ((const uint4*)(A  + (size_t)(rb*128 + row) * EMBED + kt))[q];
            ((uint4*)Bs)[c] = ((const uint4*)(Bt + (size_t)(nb*128 + row) * EMBED + kt))[q];
        }
        __syncthreads();
        f16x8 af[2], bf[8];
        #pragma unroll
        for (int mt = 0; mt < 2; mt++) af[mt] = *(const f16x8*)&As[w*32 + mt*16 + m16][kq*8];
        #pragma unroll
        for (int nt = 0; nt < 8; nt++) bf[nt] = *(const f16x8*)&Bs[nt*16 + m16][kq*8];
        #pragma unroll
        for (int mt = 0; mt < 2; mt++)
            #pragma unroll
            for (int nt = 0; nt < 8; nt++)
                acc[mt][nt] = __builtin_amdgcn_mfma_f32_16x16x32_f16(af[mt], bf[nt], acc[mt][nt], 0, 0, 0);
    }
    #pragma unroll
    for (int mt = 0; mt < 2; mt++)
        #pragma unroll
        for (int nt = 0; nt < 8; nt++) {
            int grow = nb*128 + nt*16 + m16;
            float bo = bias[cell * G4 + grow];
            #pragma unroll
            for (int i = 0; i < 4; i++) {
                int r = rb*128 + w*32 + mt*16 + kq*4 + i;
                if (cid_r[r] == cell) {
                    int bb = r >> 8, tt = r & 255;
                    Gin[((size_t)tt * G4 + grow) * BATCH + bb] = acc[mt][nt][i] + bo;
                }
            }
        }
}

// ================= persistent scan kernel: 64 blocks =================
// Barrier redesign vs previous version:
//  - per-block flag (release-fence + relaxed agent store) instead of 64 serialized
//    atomic RMWs on one word
//  - wave 0's 64 lanes poll all 64 flags (coalesced, acquire => L2 inv rides along),
//    no s_sleep quantization
//  - hs kept in LDS for the whole scan (64KB), dumped coalesced at the end: no dirty
//    hs lines for the per-step release writeback, no partial-line write amplification
//  - Gin gate values prefetched at top of step, latency hidden under the flag wait
//  - cell ids staged once into LDS (u8)
__device__ __forceinline__ float sigf(float x)   { return 1.f / (1.f + __expf(-x)); }
__device__ __forceinline__ float tanh_s(float x) { float e = __expf(2.f * x); return 1.f - 2.f / (e + 1.f); }

// dynamic LDS layout (bytes):
//  hs_lds   _Float16 [256][128]  65536
//  gate_lds float    [2*32*17]    4352
//  cid_lds  u8       [256*16]     4096
#define SCAN_LDS_BYTES (65536 + 4352 + 4096)

__global__ __launch_bounds__(256) void scan_kernel(
    const float* __restrict__ Whh,     // [2][2048][512]
    const float* __restrict__ init_h,  // [16][512]
    const float* __restrict__ init_c,  // [16][512]
    const float* __restrict__ Gin,     // [256][2048][16]
    const int* __restrict__ cids_t,    // [256][16]
    _Float16* __restrict__ h_pub,      // [2][16][512]
    _Float16* __restrict__ hs,         // [4096][512]  rows r=b*256+t
    unsigned int* __restrict__ flags,  // [64] per-block step counters
    float* __restrict__ outHT, float* __restrict__ outCT)
{
    extern __shared__ char smem[];
    _Float16*      hs_lds   = (_Float16*)smem;                   // [256*128]
    float*         gate_lds = (float*)(smem + 65536);            // [2*32*17]
    unsigned char* cid_lds  = (unsigned char*)(smem + 65536 + 4352); // [4096]

    const int tid = threadIdx.x, lane = tid & 63, w = tid >> 6;
    const int blk = blockIdx.x;
    const int cell = w >> 1, mt = w & 1;
    const int m16 = lane & 15, kq = lane >> 4;

    // ---- load this wave's A fragments (W_hh rows) into registers, f32->f16 ----
    int r    = mt * 16 + m16;          // 0..31 row index within block-slice
    int g    = r >> 3, ul = r & 7;
    int grow = g * HIDDEN + blk * 8 + ul;
    f16x8 af[16];
    const float* wrow = Whh + ((size_t)cell * G4 + grow) * HIDDEN;
    #pragma unroll
    for (int kt = 0; kt < 16; kt++) {
        int k0 = kt * 32 + kq * 8;
        float4 a0 = *(const float4*)(wrow + k0);
        float4 a1 = *(const float4*)(wrow + k0 + 4);
        f16x8 f;
        f[0]=(_Float16)a0.x; f[1]=(_Float16)a0.y; f[2]=(_Float16)a0.z; f[3]=(_Float16)a0.w;
        f[4]=(_Float16)a1.x; f[5]=(_Float16)a1.y; f[6]=(_Float16)a1.z; f[7]=(_Float16)a1.w;
        af[kt] = f;
    }

    // ---- stage cell ids into LDS ----
    for (int i = tid; i < T_STEPS * BATCH; i += 256)
        cid_lds[i] = (unsigned char)cids_t[i];

    // ---- per-thread LSTM state: thread (tid<128) owns (b=tid>>3, uu=tid&7) ----
    const int ub = tid >> 3, uu = tid & 7;
    const int ug = blk * 8 + uu;
    float c_st = 0.f;
    if (tid < 128) {
        c_st = init_c[ub * HIDDEN + ug];
        float h0 = init_h[ub * HIDDEN + ug];
        h_pub[ub * HIDDEN + ug] = (_Float16)h0;     // buffer 0
    }
    __syncthreads();
    if (tid == 0) {
        __builtin_amdgcn_fence(__ATOMIC_RELEASE, "agent");
        __hip_atomic_store(&flags[blk], 1u, __ATOMIC_RELAXED, __HIP_MEMORY_SCOPE_AGENT);
    }

    for (int t = 0; t < T_STEPS; t++) {
        // ---- prefetch this step's Gin gate values (independent of the barrier) ----
        float pf0, pf1, pf2, pf3;
        if (tid < 128) {
            const float* gbase = Gin + (size_t)t * (G4 * BATCH);
            pf0 = gbase[((size_t)0 * HIDDEN + ug) * BATCH + ub];
            pf1 = gbase[((size_t)1 * HIDDEN + ug) * BATCH + ub];
            pf2 = gbase[((size_t)2 * HIDDEN + ug) * BATCH + ub];
            pf3 = gbase[((size_t)3 * HIDDEN + ug) * BATCH + ub];
        }

        // ---- wait until every block has published h for step t ----
        if (w == 0) {
            const unsigned tgt = (unsigned)(t + 1);
            while (__hip_atomic_load(&flags[lane], __ATOMIC_ACQUIRE, __HIP_MEMORY_SCOPE_AGENT) < tgt) {}
        }
        __syncthreads();

        // ---- h_t @ W_hh^T for both cells ----
        const _Float16* hb = h_pub + (size_t)(t & 1) * (BATCH * HIDDEN);
        f32x4 acc = (f32x4){0.f, 0.f, 0.f, 0.f};
        #pragma unroll
        for (int kt = 0; kt < 16; kt++) {
            int k0 = kt * 32 + kq * 8;
            f16x8 bfrag = *(const f16x8*)(hb + m16 * HIDDEN + k0);   // row b=m16
            acc = __builtin_amdgcn_mfma_f32_16x16x32_f16(af[kt], bfrag, acc, 0, 0, 0);
        }
        #pragma unroll
        for (int i = 0; i < 4; i++) {
            int rr = mt * 16 + kq * 4 + i;                 // D row (gate-row space)
            gate_lds[(cell * 32 + rr) * 17 + m16] = acc[i]; // D col = b = lane&15
        }
        __syncthreads();

        // ---- pointwise LSTM update ----
        if (tid < 128) {
            int cid = cid_lds[t * BATCH + ub];
            float gi = gate_lds[(cid * 32 +  0 + uu) * 17 + ub] + pf0;
            float gf = gate_lds[(cid * 32 +  8 + uu) * 17 + ub] + pf1;
            float gg = gate_lds[(cid * 32 + 16 + uu) * 17 + ub] + pf2;
            float go = gate_lds[(cid * 32 + 24 + uu) * 17 + ub] + pf3;
            float is = sigf(gi), fs = sigf(gf), os = sigf(go);
            c_st = fs * c_st + is * tanh_s(gg);
            float hn = os * tanh_s(c_st);
            _Float16 hh = (_Float16)hn;
            h_pub[(size_t)((t + 1) & 1) * (BATCH * HIDDEN) + ub * HIDDEN + ug] = hh;
            hs_lds[t * 128 + tid] = hh;
            if (t == T_STEPS - 1) {
                outHT[ub * HIDDEN + ug] = hn;
                outCT[ub * HIDDEN + ug] = c_st;
            }
        }
        __syncthreads();
        if (tid == 0) {
            __builtin_amdgcn_fence(__ATOMIC_RELEASE, "agent");
            __hip_atomic_store(&flags[blk], (unsigned)(t + 2), __ATOMIC_RELAXED, __HIP_MEMORY_SCOPE_AGENT);
        }
    }

    // ---- dump hs from LDS to global, 16B chunks ----
    __syncthreads();
    for (int id = tid; id < T_STEPS * BATCH; id += 256) {
        int t = id >> 4, b = id & 15;
        uint4 v = *(const uint4*)(hs_lds + t * 128 + b * 8);
        *(uint4*)(hs + ((size_t)b * T_STEPS + t) * HIDDEN + blk * 8) = v;
    }
}

// ================= output GEMM: hs[4096,512] x Wout[32000,512]^T + b_out =================
__global__ __launch_bounds__(256) void gemm_out_kernel(
    const _Float16* __restrict__ A,   // hs [4096][512]
    const _Float16* __restrict__ Bt,  // Wout [32000][512]
    const float* __restrict__ bout,   // [32000]
    float* __restrict__ C)            // [4096][32000]
{
    __shared__ __attribute__((aligned(16))) _Float16 As[128][32];
    __shared__ __attribute__((aligned(16))) _Float16 Bs[128][32];
    const int tid = threadIdx.x, lane = tid & 63, w = tid >> 6;
    const int m16 = lane & 15, kq = lane >> 4;
    const int rb = blockIdx.x, nb = blockIdx.y;
    f32x4 acc[2][8];
    for (int mt = 0; mt < 2; mt++) for (int nt = 0; nt < 8; nt++) acc[mt][nt] = (f32x4){0.f,0.f,0.f,0.f};

    for (int kt = 0; kt < HIDDEN; kt += 32) {
        __syncthreads();
        #pragma unroll
        for (int c = tid; c < 512; c += 256) {
            int row = c >> 2, q = c & 3;
            ((uint4*)As)[c] = ((const uint4*)(A  + (size_t)(rb*128 + row) * HIDDEN + kt))[q];
            ((uint4*)Bs)[c] = ((const uint4*)(Bt + (size_t)(nb*128 + row) * HIDDEN + kt))[q];
        }
        __syncthreads();
        f16x8 af[2], bf[8];
        #pragma unroll
        for (int mt = 0; mt < 2; mt++) af[mt] = *(const f16x8*)&As[w*32 + mt*16 + m16][kq*8];
        #pragma unroll
        for (int nt = 0; nt < 8; nt++) bf[nt] = *(const f16x8*)&Bs[nt*16 + m16][kq*8];
        #pragma unroll
        for (int mt = 0; mt < 2; mt++)
            #pragma unroll
            for (int nt = 0; nt < 8; nt++)
                acc[mt][nt] = __builtin_amdgcn_mfma_f32_16x16x32_f16(af[mt], bf[nt], acc[mt][nt], 0, 0, 0);
    }
    #pragma unroll
    for (int mt = 0; mt < 2; mt++)
        #pragma unroll
        for (int nt = 0; nt < 8; nt++) {
            int vcol = nb*128 + nt*16 + m16;
            float bo = bout[vcol];
            #pragma unroll
            for (int i = 0; i < 4; i++) {
                int r = rb*128 + w*32 + mt*16 + kq*4 + i;
                C[(size_t)r * VOCAB + vcol] = acc[mt][nt][i] + bo;
            }
        }
}

// ================= log_softmax over 32000, row cached in dynamic LDS =================
__global__ __launch_bounds__(1024) void lsm_kernel(float* __restrict__ C)
{
    extern __shared__ float sm[];        // 32000 row + 64 scratch
    float* red = sm + VOCAB;
    const int tid = threadIdx.x, lane = tid & 63, wid = tid >> 6;
    float* rowp = C + (size_t)blockIdx.x * VOCAB;
    const float4* src4 = (const float4*)rowp;
    float4* dst4 = (float4*)rowp;
    float4* row4 = (float4*)sm;

    float m = -3.0e38f;
    for (int i = tid; i < VOCAB/4; i += 1024) {
        float4 v = src4[i];
        row4[i] = v;
        m = fmaxf(m, fmaxf(fmaxf(v.x, v.y), fmaxf(v.z, v.w)));
    }
    #pragma unroll
    for (int o = 32; o; o >>= 1) m = fmaxf(m, __shfl_xor(m, o));
    if (lane == 0) red[wid] = m;
    __syncthreads();
    if (tid == 0) {
        float mm = red[0];
        for (int i = 1; i < 16; i++) mm = fmaxf(mm, red[i]);
        red[16] = mm;
    }
    __syncthreads();
    m = red[16];

    float s = 0.f;
    for (int i = tid; i < VOCAB/4; i += 1024) {
        float4 v = row4[i];
        s += __expf(v.x - m) + __expf(v.y - m) + __expf(v.z - m) + __expf(v.w - m);
    }
    #pragma unroll
    for (int o = 32; o; o >>= 1) s += __shfl_xor(s, o);
    if (lane == 0) red[wid + 32] = s;
    __syncthreads();
    if (tid == 0) {
        float ss = 0.f;
        for (int i = 0; i < 16; i++) ss += red[32 + i];
        red[17] = ss;
    }
    __syncthreads();
    const float lse = m + __logf(red[17]);

    for (int i = tid; i < VOCAB/4; i += 1024) {
        float4 v = row4[i];
        v.x -= lse; v.y -= lse; v.z -= lse; v.w -= lse;
        dst4[i] = v;
    }
}

// ================= launcher =================
extern "C" void kernel_launch(void* const* d_in, const int* in_sizes, int n_in,
                              void* d_out, int out_size, void* d_ws, size_t ws_size,
                              hipStream_t stream) {
    (void)in_sizes; (void)n_in; (void)out_size; (void)ws_size;
    const int*   x      = (const int*)d_in[0];
    const int*   assign = (const int*)d_in[1];
    const float* init_h = (const float*)d_in[2];
    const float* init_c = (const float*)d_in[3];
    const float* embt   = (const float*)d_in[4];
    const float* Wih    = (const float*)d_in[5];
    const float* Whh    = (const float*)d_in[6];
    const float* bias   = (const float*)d_in[7];
    const float* Wout   = (const float*)d_in[8];
    const float* bout   = (const float*)d_in[9];
    float* out = (float*)d_out;
    char*  ws  = (char*)d_ws;

    float*        Gin    = (float*)(ws + OFF_GIN);
    _Float16*     wout_h = (_Float16*)(ws + OFF_WOUT);
    _Float16*     hs     = (_Float16*)(ws + OFF_HS);
    _Float16*     emb_h  = (_Float16*)(ws + OFF_EMB);
    _Float16*     wih_h  = (_Float16*)(ws + OFF_WIH);
    _Float16*     h_pub  = (_Float16*)(ws + OFF_HPUB);
    int*          cids_t = (int*)(ws + OFF_CIDT);
    int*          cid_r  = (int*)(ws + OFF_CIDR);
    unsigned int* flags  = (unsigned int*)(ws + OFF_FLAGS);

    float* outHT = out + (size_t)NTOK * VOCAB;          // 131,072,000
    float* outCT = outHT + BATCH * HIDDEN;

    prep_kernel<<<(P_SE + 255) / 256, 256, 0, stream>>>(
        x, assign, Wih, Wout, embt, wih_h, wout_h, emb_h, cids_t, cid_r, flags);

    gin_gemm_kernel<<<dim3(NTOK/128, G4/128, 2), 256, 0, stream>>>(
        emb_h, wih_h, bias, cid_r, Gin);

    hipFuncSetAttribute((const void*)scan_kernel,
                        hipFuncAttributeMaxDynamicSharedMemorySize, SCAN_LDS_BYTES);
    scan_kernel<<<NBLK_SCAN, 256, SCAN_LDS_BYTES, stream>>>(
        Whh, init_h, init_c, Gin, cids_t, h_pub, hs, flags, outHT, outCT);

    gemm_out_kernel<<<dim3(NTOK/128, VOCAB/128), 256, 0, stream>>>(
        hs, wout_h, bout, out);

    static_assert(VOCAB % 4 == 0, "");
    int lsm_lds = (VOCAB + 64) * (int)sizeof(float);
    hipFuncSetAttribute((const void*)lsm_kernel,
                        hipFuncAttributeMaxDynamicSharedMemorySize, lsm_lds);
    lsm_kernel<<<NTOK, 1024, lsm_lds, stream>>>(out);
}

// Round 2
// 2398.862 us; speedup vs baseline: 1.4832x; 1.1288x over previous
//
#include <hip/hip_runtime.h>

// ---------------- problem constants ----------------
#define T_STEPS 256
#define BATCH   16
#define EMBED   256
#define HIDDEN  512
#define G4      2048      // 4*HIDDEN
#define VOCAB   32000
#define NTOK    4096      // B*T
#define NBLK_SCAN 64

typedef _Float16 f16x8 __attribute__((ext_vector_type(8)));
typedef float    f32x4 __attribute__((ext_vector_type(4)));

// ---------------- ws layout (bytes) ----------------
// Gin   f32 [256][2048][16]   33,554,432
// Wout  f16 [32000][512]      32,768,000
// hs    f16 [4096][512]        4,194,304
// emb   f16 [4096][256]        2,097,152
// Wih   f16 [2][2048][256]     2,097,152
// hpub  f16 [2][64][16][8]        32,768   (block-contiguous layout)
// cidt  i32 [256][16]             16,384
// cidr  i32 [4096]                16,384
// flags u32 [257]                  2,048
#define OFF_GIN    0
#define OFF_WOUT   33554432
#define OFF_HS     66322432
#define OFF_EMB    70516736
#define OFF_WIH    72613888
#define OFF_HPUB   74711040
#define OFF_CIDT   74743808
#define OFF_CIDR   74760192
#define OFF_FLAGS  74776576

// ================= prep: dtype conversions, gathers, flag zeroing =================
#define P_SA 4096000
#define P_SB (P_SA + 262144)
#define P_SC (P_SB + 262144)
#define P_SD (P_SC + 4096)
#define P_SE (P_SD + 257)

__global__ __launch_bounds__(256) void prep_kernel(
    const int* __restrict__ x, const int* __restrict__ assign,
    const float* __restrict__ Wih, const float* __restrict__ Wout,
    const float* __restrict__ embt,
    _Float16* __restrict__ wih_h, _Float16* __restrict__ wout_h,
    _Float16* __restrict__ emb_h, int* __restrict__ cids_t,
    int* __restrict__ cid_r, unsigned int* __restrict__ flags)
{
    size_t id = (size_t)blockIdx.x * 256 + threadIdx.x;
    if (id < P_SA) {
        float4 v = ((const float4*)Wout)[id];
        _Float16* o = wout_h + id * 4;
        o[0] = (_Float16)v.x; o[1] = (_Float16)v.y; o[2] = (_Float16)v.z; o[3] = (_Float16)v.w;
    } else if (id < P_SB) {
        size_t j = id - P_SA;
        float4 v = ((const float4*)Wih)[j];
        _Float16* o = wih_h + j * 4;
        o[0] = (_Float16)v.x; o[1] = (_Float16)v.y; o[2] = (_Float16)v.z; o[3] = (_Float16)v.w;
    } else if (id < P_SC) {
        size_t j = id - P_SB;
        int r  = (int)(j >> 6);      // token row 0..4095  (r = b*256+t)
        int e4 = (int)(j & 63);
        float4 v = ((const float4*)(embt + (size_t)x[r] * EMBED))[e4];
        _Float16* o = emb_h + (size_t)r * EMBED + e4 * 4;
        o[0] = (_Float16)v.x; o[1] = (_Float16)v.y; o[2] = (_Float16)v.z; o[3] = (_Float16)v.w;
    } else if (id < P_SD) {
        int j = (int)(id - P_SC);
        int b = j >> 8, t = j & 255;
        int c = assign[x[j]];
        cid_r[j] = c;
        cids_t[t * BATCH + b] = c;
    } else if (id < P_SE) {
        flags[id - P_SD] = 0u;
    }
}

// ================= Gin GEMM: emb[4096,256] x Wih[c][2048,256]^T, cell-selected scatter =================
__global__ __launch_bounds__(256) void gin_gemm_kernel(
    const _Float16* __restrict__ A,      // emb_h [4096][256]
    const _Float16* __restrict__ WihH,   // [2][2048][256]
    const float* __restrict__ bias,      // [2][2048]
    const int* __restrict__ cid_r,       // [4096]
    float* __restrict__ Gin)             // [256][2048][16]
{
    __shared__ __attribute__((aligned(16))) _Float16 As[128][32];
    __shared__ __attribute__((aligned(16))) _Float16 Bs[128][32];
    const int tid = threadIdx.x, lane = tid & 63, w = tid >> 6;
    const int m16 = lane & 15, kq = lane >> 4;
    const int rb = blockIdx.x, nb = blockIdx.y, cell = blockIdx.z;
    const _Float16* Bt = WihH + (size_t)cell * G4 * EMBED;
    f32x4 acc[2][8];
    for (int mt = 0; mt < 2; mt++) for (int nt = 0; nt < 8; nt++) acc[mt][nt] = (f32x4){0.f,0.f,0.f,0.f};

    for (int kt = 0; kt < EMBED; kt += 32) {
        __syncthreads();
        #pragma unroll
        for (int c = tid; c < 512; c += 256) {
            int row = c >> 2, q = c & 3;
            ((uint4*)As)[c] = ((const uint4*)(A  + (size_t)(rb*128 + row) * EMBED + kt))[q];
            ((uint4*)Bs)[c] = ((const uint4*)(Bt + (size_t)(nb*128 + row) * EMBED + kt))[q];
        }
        __syncthreads();
        f16x8 af[2], bf[8];
        #pragma unroll
        for (int mt = 0; mt < 2; mt++) af[mt] = *(const f16x8*)&As[w*32 + mt*16 + m16][kq*8];
        #pragma unroll
        for (int nt = 0; nt < 8; nt++) bf[nt] = *(const f16x8*)&Bs[nt*16 + m16][kq*8];
        #pragma unroll
        for (int mt = 0; mt < 2; mt++)
            #pragma unroll
            for (int nt = 0; nt < 8; nt++)
                acc[mt][nt] = __builtin_amdgcn_mfma_f32_16x16x32_f16(af[mt], bf[nt], acc[mt][nt], 0, 0, 0);
    }
    #pragma unroll
    for (int mt = 0; mt < 2; mt++)
        #pragma unroll
        for (int nt = 0; nt < 8; nt++) {
            int grow = nb*128 + nt*16 + m16;
            float bo = bias[cell * G4 + grow];
            #pragma unroll
            for (int i = 0; i < 4; i++) {
                int r = rb*128 + w*32 + mt*16 + kq*4 + i;
                if (cid_r[r] == cell) {
                    int bb = r >> 8, tt = r & 255;
                    Gin[((size_t)tt * G4 + grow) * BATCH + bb] = acc[mt][nt][i] + bo;
                }
            }
        }
}

// ================= persistent scan kernel: 64 blocks =================
// Sync redesign vs previous version:
//  - h_pub layout [buf][src_blk][16][8]: each producer's 256B chunk is 4 full
//    aligned 64B lines (was 16 partial lines at stride 1KB)
//  - h published via relaxed agent-scope 4B atomic stores (f16 pairs packed with
//    shfl_xor): write-through to the coherence point, L2 stays clean, so the
//    per-step release fence has nothing to write back
//  - poll with RELAXED atomic loads + ONE acquire fence after the loop (the old
//    per-iteration acquire load emitted buffer_inv every spin)
//  - consumer MFMA B-fragment for (kt,kq) is h_pub2[kt*4+kq][m16][0..7]:
//    a contiguous 16B load
__device__ __forceinline__ float sigf(float x)   { return 1.f / (1.f + __expf(-x)); }
__device__ __forceinline__ float tanh_s(float x) { float e = __expf(2.f * x); return 1.f - 2.f / (e + 1.f); }

// dynamic LDS layout (bytes):
//  hs_lds   _Float16 [256][128]  65536
//  gate_lds float    [2*32*17]    4352
//  cid_lds  u8       [256*16]     4096
#define SCAN_LDS_BYTES (65536 + 4352 + 4096)

__global__ __launch_bounds__(256) void scan_kernel(
    const float* __restrict__ Whh,     // [2][2048][512]
    const float* __restrict__ init_h,  // [16][512]
    const float* __restrict__ init_c,  // [16][512]
    const float* __restrict__ Gin,     // [256][2048][16]
    const int* __restrict__ cids_t,    // [256][16]
    _Float16* __restrict__ h_pub,      // [2][64][16][8]  block-contiguous
    _Float16* __restrict__ hs,         // [4096][512]  rows r=b*256+t
    unsigned int* __restrict__ flags,  // [64] per-block step counters
    float* __restrict__ outHT, float* __restrict__ outCT)
{
    extern __shared__ char smem[];
    _Float16*      hs_lds   = (_Float16*)smem;                   // [256*128]
    float*         gate_lds = (float*)(smem + 65536);            // [2*32*17]
    unsigned char* cid_lds  = (unsigned char*)(smem + 65536 + 4352); // [4096]

    const int tid = threadIdx.x, lane = tid & 63, w = tid >> 6;
    const int blk = blockIdx.x;
    const int cell = w >> 1, mt = w & 1;
    const int m16 = lane & 15, kq = lane >> 4;

    // ---- load this wave's A fragments (W_hh rows) into registers, f32->f16 ----
    int r    = mt * 16 + m16;          // 0..31 row index within block-slice
    int g    = r >> 3, ul = r & 7;
    int grow = g * HIDDEN + blk * 8 + ul;
    f16x8 af[16];
    const float* wrow = Whh + ((size_t)cell * G4 + grow) * HIDDEN;
    #pragma unroll
    for (int kt = 0; kt < 16; kt++) {
        int k0 = kt * 32 + kq * 8;
        float4 a0 = *(const float4*)(wrow + k0);
        float4 a1 = *(const float4*)(wrow + k0 + 4);
        f16x8 f;
        f[0]=(_Float16)a0.x; f[1]=(_Float16)a0.y; f[2]=(_Float16)a0.z; f[3]=(_Float16)a0.w;
        f[4]=(_Float16)a1.x; f[5]=(_Float16)a1.y; f[6]=(_Float16)a1.z; f[7]=(_Float16)a1.w;
        af[kt] = f;
    }

    // ---- stage cell ids into LDS ----
    for (int i = tid; i < T_STEPS * BATCH; i += 256)
        cid_lds[i] = (unsigned char)cids_t[i];

    // ---- per-thread LSTM state: thread (tid<128) owns (b=tid>>3, uu=tid&7) ----
    const int ub = tid >> 3, uu = tid & 7;
    const int ug = blk * 8 + uu;
    float c_st = 0.f;
    if (tid < 128) {
        c_st = init_c[ub * HIDDEN + ug];
        float h0 = init_h[ub * HIDDEN + ug];
        _Float16 hh = (_Float16)h0;
        unsigned hu = (unsigned)__builtin_bit_cast(unsigned short, hh);
        unsigned other = (unsigned)__shfl_xor((int)hu, 1);
        if (!(uu & 1)) {
            unsigned packed = hu | (other << 16);
            unsigned* dst = (unsigned*)(h_pub + (size_t)blk * 128 + ub * 8 + uu);
            __hip_atomic_store(dst, packed, __ATOMIC_RELAXED, __HIP_MEMORY_SCOPE_AGENT);
        }
    }
    __syncthreads();
    if (tid == 0) {
        __builtin_amdgcn_fence(__ATOMIC_RELEASE, "agent");
        __hip_atomic_store(&flags[blk], 1u, __ATOMIC_RELAXED, __HIP_MEMORY_SCOPE_AGENT);
    }

    for (int t = 0; t < T_STEPS; t++) {
        // ---- prefetch this step's Gin gate values (independent of the barrier) ----
        float pf0, pf1, pf2, pf3;
        if (tid < 128) {
            const float* gbase = Gin + (size_t)t * (G4 * BATCH);
            pf0 = gbase[((size_t)0 * HIDDEN + ug) * BATCH + ub];
            pf1 = gbase[((size_t)1 * HIDDEN + ug) * BATCH + ub];
            pf2 = gbase[((size_t)2 * HIDDEN + ug) * BATCH + ub];
            pf3 = gbase[((size_t)3 * HIDDEN + ug) * BATCH + ub];
        }

        // ---- wait until every block has published h for step t ----
        if (w == 0) {
            const unsigned tgt = (unsigned)(t + 1);
            while (__hip_atomic_load(&flags[lane], __ATOMIC_RELAXED, __HIP_MEMORY_SCOPE_AGENT) < tgt) {}
            __builtin_amdgcn_fence(__ATOMIC_ACQUIRE, "agent");
        }
        __syncthreads();

        // ---- h_t @ W_hh^T for both cells ----
        const _Float16* hb = h_pub + (size_t)(t & 1) * (NBLK_SCAN * 128);
        f32x4 acc = (f32x4){0.f, 0.f, 0.f, 0.f};
        #pragma unroll
        for (int kt = 0; kt < 16; kt++) {
            int sb = kt * 4 + kq;                            // source block of this K-chunk
            f16x8 bfrag = *(const f16x8*)(hb + (sb * 16 + m16) * 8);
            acc = __builtin_amdgcn_mfma_f32_16x16x32_f16(af[kt], bfrag, acc, 0, 0, 0);
        }
        #pragma unroll
        for (int i = 0; i < 4; i++) {
            int rr = mt * 16 + kq * 4 + i;                 // D row (gate-row space)
            gate_lds[(cell * 32 + rr) * 17 + m16] = acc[i]; // D col = b = lane&15
        }
        __syncthreads();

        // ---- pointwise LSTM update ----
        if (tid < 128) {
            int cid = cid_lds[t * BATCH + ub];
            float gi = gate_lds[(cid * 32 +  0 + uu) * 17 + ub] + pf0;
            float gf = gate_lds[(cid * 32 +  8 + uu) * 17 + ub] + pf1;
            float gg = gate_lds[(cid * 32 + 16 + uu) * 17 + ub] + pf2;
            float go = gate_lds[(cid * 32 + 24 + uu) * 17 + ub] + pf3;
            float is = sigf(gi), fs = sigf(gf), os = sigf(go);
            c_st = fs * c_st + is * tanh_s(gg);
            float hn = os * tanh_s(c_st);
            _Float16 hh = (_Float16)hn;
            // publish h_{t+1}: pack f16 pair, write-through 4B atomic store
            unsigned hu = (unsigned)__builtin_bit_cast(unsigned short, hh);
            unsigned other = (unsigned)__shfl_xor((int)hu, 1);
            if (!(uu & 1)) {
                unsigned packed = hu | (other << 16);
                unsigned* dst = (unsigned*)(h_pub
                    + (size_t)((t + 1) & 1) * (NBLK_SCAN * 128)
                    + (size_t)blk * 128 + ub * 8 + uu);
                __hip_atomic_store(dst, packed, __ATOMIC_RELAXED, __HIP_MEMORY_SCOPE_AGENT);
            }
            hs_lds[t * 128 + tid] = hh;
            if (t == T_STEPS - 1) {
                outHT[ub * HIDDEN + ug] = hn;
                outCT[ub * HIDDEN + ug] = c_st;
            }
        }
        __syncthreads();
        if (tid == 0) {
            __builtin_amdgcn_fence(__ATOMIC_RELEASE, "agent");
            __hip_atomic_store(&flags[blk], (unsigned)(t + 2), __ATOMIC_RELAXED, __HIP_MEMORY_SCOPE_AGENT);
        }
    }

    // ---- dump hs from LDS to global, 16B chunks ----
    __syncthreads();
    for (int id = tid; id < T_STEPS * BATCH; id += 256) {
        int t = id >> 4, b = id & 15;
        uint4 v = *(const uint4*)(hs_lds + t * 128 + b * 8);
        *(uint4*)(hs + ((size_t)b * T_STEPS + t) * HIDDEN + blk * 8) = v;
    }
}

// ================= output GEMM: hs[4096,512] x Wout[32000,512]^T + b_out =================
__global__ __launch_bounds__(256) void gemm_out_kernel(
    const _Float16* __restrict__ A,   // hs [4096][512]
    const _Float16* __restrict__ Bt,  // Wout [32000][512]
    const float* __restrict__ bout,   // [32000]
    float* __restrict__ C)            // [4096][32000]
{
    __shared__ __attribute__((aligned(16))) _Float16 As[128][32];
    __shared__ __attribute__((aligned(16))) _Float16 Bs[128][32];
    const int tid = threadIdx.x, lane = tid & 63, w = tid >> 6;
    const int m16 = lane & 15, kq = lane >> 4;
    const int rb = blockIdx.x, nb = blockIdx.y;
    f32x4 acc[2][8];
    for (int mt = 0; mt < 2; mt++) for (int nt = 0; nt < 8; nt++) acc[mt][nt] = (f32x4){0.f,0.f,0.f,0.f};

    for (int kt = 0; kt < HIDDEN; kt += 32) {
        __syncthreads();
        #pragma unroll
        for (int c = tid; c < 512; c += 256) {
            int row = c >> 2, q = c & 3;
            ((uint4*)As)[c] = ((const uint4*)(A  + (size_t)(rb*128 + row) * HIDDEN + kt))[q];
            ((uint4*)Bs)[c] = ((const uint4*)(Bt + (size_t)(nb*128 + row) * HIDDEN + kt))[q];
        }
        __syncthreads();
        f16x8 af[2], bf[8];
        #pragma unroll
        for (int mt = 0; mt < 2; mt++) af[mt] = *(const f16x8*)&As[w*32 + mt*16 + m16][kq*8];
        #pragma unroll
        for (int nt = 0; nt < 8; nt++) bf[nt] = *(const f16x8*)&Bs[nt*16 + m16][kq*8];
        #pragma unroll
        for (int mt = 0; mt < 2; mt++)
            #pragma unroll
            for (int nt = 0; nt < 8; nt++)
                acc[mt][nt] = __builtin_amdgcn_mfma_f32_16x16x32_f16(af[mt], bf[nt], acc[mt][nt], 0, 0, 0);
    }
    #pragma unroll
    for (int mt = 0; mt < 2; mt++)
        #pragma unroll
        for (int nt = 0; nt < 8; nt++) {
            int vcol = nb*128 + nt*16 + m16;
            float bo = bout[vcol];
            #pragma unroll
            for (int i = 0; i < 4; i++) {
                int r = rb*128 + w*32 + mt*16 + kq*4 + i;
                C[(size_t)r * VOCAB + vcol] = acc[mt][nt][i] + bo;
            }
        }
}

// ================= log_softmax over 32000, row cached in dynamic LDS =================
__global__ __launch_bounds__(1024) void lsm_kernel(float* __restrict__ C)
{
    extern __shared__ float sm[];        // 32000 row + 64 scratch
    float* red = sm + VOCAB;
    const int tid = threadIdx.x, lane = tid & 63, wid = tid >> 6;
    float* rowp = C + (size_t)blockIdx.x * VOCAB;
    const float4* src4 = (const float4*)rowp;
    float4* dst4 = (float4*)rowp;
    float4* row4 = (float4*)sm;

    float m = -3.0e38f;
    for (int i = tid; i < VOCAB/4; i += 1024) {
        float4 v = src4[i];
        row4[i] = v;
        m = fmaxf(m, fmaxf(fmaxf(v.x, v.y), fmaxf(v.z, v.w)));
    }
    #pragma unroll
    for (int o = 32; o; o >>= 1) m = fmaxf(m, __shfl_xor(m, o));
    if (lane == 0) red[wid] = m;
    __syncthreads();
    if (tid == 0) {
        float mm = red[0];
        for (int i = 1; i < 16; i++) mm = fmaxf(mm, red[i]);
        red[16] = mm;
    }
    __syncthreads();
    m = red[16];

    float s = 0.f;
    for (int i = tid; i < VOCAB/4; i += 1024) {
        float4 v = row4[i];
        s += __expf(v.x - m) + __expf(v.y - m) + __expf(v.z - m) + __expf(v.w - m);
    }
    #pragma unroll
    for (int o = 32; o; o >>= 1) s += __shfl_xor(s, o);
    if (lane == 0) red[wid + 32] = s;
    __syncthreads();
    if (tid == 0) {
        float ss = 0.f;
        for (int i = 0; i < 16; i++) ss += red[32 + i];
        red[17] = ss;
    }
    __syncthreads();
    const float lse = m + __logf(red[17]);

    for (int i = tid; i < VOCAB/4; i += 1024) {
        float4 v = row4[i];
        v.x -= lse; v.y -= lse; v.z -= lse; v.w -= lse;
        dst4[i] = v;
    }
}

// ================= launcher =================
extern "C" void kernel_launch(void* const* d_in, const int* in_sizes, int n_in,
                              void* d_out, int out_size, void* d_ws, size_t ws_size,
                              hipStream_t stream) {
    (void)in_sizes; (void)n_in; (void)out_size; (void)ws_size;
    const int*   x      = (const int*)d_in[0];
    const int*   assign = (const int*)d_in[1];
    const float* init_h = (const float*)d_in[2];
    const float* init_c = (const float*)d_in[3];
    const float* embt   = (const float*)d_in[4];
    const float* Wih    = (const float*)d_in[5];
    const float* Whh    = (const float*)d_in[6];
    const float* bias   = (const float*)d_in[7];
    const float* Wout   = (const float*)d_in[8];
    const float* bout   = (const float*)d_in[9];
    float* out = (float*)d_out;
    char*  ws  = (char*)d_ws;

    float*        Gin    = (float*)(ws + OFF_GIN);
    _Float16*     wout_h = (_Float16*)(ws + OFF_WOUT);
    _Float16*     hs     = (_Float16*)(ws + OFF_HS);
    _Float16*     emb_h  = (_Float16*)(ws + OFF_EMB);
    _Float16*     wih_h  = (_Float16*)(ws + OFF_WIH);
    _Float16*     h_pub  = (_Float16*)(ws + OFF_HPUB);
    int*          cids_t = (int*)(ws + OFF_CIDT);
    int*          cid_r  = (int*)(ws + OFF_CIDR);
    unsigned int* flags  = (unsigned int*)(ws + OFF_FLAGS);

    float* outHT = out + (size_t)NTOK * VOCAB;          // 131,072,000
    float* outCT = outHT + BATCH * HIDDEN;

    prep_kernel<<<(P_SE + 255) / 256, 256, 0, stream>>>(
        x, assign, Wih, Wout, embt, wih_h, wout_h, emb_h, cids_t, cid_r, flags);

    gin_gemm_kernel<<<dim3(NTOK/128, G4/128, 2), 256, 0, stream>>>(
        emb_h, wih_h, bias, cid_r, Gin);

    hipFuncSetAttribute((const void*)scan_kernel,
                        hipFuncAttributeMaxDynamicSharedMemorySize, SCAN_LDS_BYTES);
    scan_kernel<<<NBLK_SCAN, 256, SCAN_LDS_BYTES, stream>>>(
        Whh, init_h, init_c, Gin, cids_t, h_pub, hs, flags, outHT, outCT);

    gemm_out_kernel<<<dim3(NTOK/128, VOCAB/128), 256, 0, stream>>>(
        hs, wout_h, bout, out);

    static_assert(VOCAB % 4 == 0, "");
    int lsm_lds = (VOCAB + 64) * (int)sizeof(float);
    hipFuncSetAttribute((const void*)lsm_kernel,
                        hipFuncAttributeMaxDynamicSharedMemorySize, lsm_lds);
    lsm_kernel<<<NTOK, 1024, lsm_lds, stream>>>(out);
}